// Round 1
// baseline (201.601 us; speedup 1.0000x reference)
//
#include <hip/hip_runtime.h>
#include <hip/hip_bf16.h>
#include <math.h>

#define NNODES 8192
#define DIM 128
#define SMAX 128

__device__ __forceinline__ int edge_idx(const void* p, int e, int idx64) {
    if (idx64) return (int)((const long long*)p)[e];
    return ((const int*)p)[e];
}

// --- K0: detect index dtype (int32 vs int64) + zero slot counter ---
__global__ void k0_detect(const void* rowp, int* flags) {
    if (threadIdx.x == 0 && blockIdx.x == 0) {
        const long long* p = (const long long*)rowp;
        int is64 = 1;
        for (int i = 0; i < 4; i++) {
            long long v = p[i];
            if (v < 0 || v >= NNODES) is64 = 0;
        }
        flags[0] = is64;
        flags[1] = 0;   // ns (neighbor slot counter)
    }
}

// --- K1a: U = embed @ W1e[0:128], V = embed @ W1e[128:256]  (per-node 64-vec each) ---
__global__ __launch_bounds__(64) void k_uv(const float* embed, const float* W1e,
                                           float* U, float* V) {
    __shared__ float emb[8][DIM];
    int t = threadIdx.x;
    int n0 = blockIdx.x * 8;
    for (int i = t; i < 8 * DIM; i += 64)
        emb[i / DIM][i % DIM] = embed[(size_t)(n0 + i / DIM) * DIM + (i % DIM)];
    __syncthreads();
    float au[8] = {0}, av[8] = {0};
    for (int d = 0; d < DIM; d++) {
        float w1 = W1e[d * 64 + t];
        float w2 = W1e[(DIM + d) * 64 + t];
#pragma unroll
        for (int i = 0; i < 8; i++) { au[i] += emb[i][d] * w1; av[i] += emb[i][d] * w2; }
    }
    for (int i = 0; i < 8; i++) {
        U[(size_t)(n0 + i) * 64 + t] = au[i];
        V[(size_t)(n0 + i) * 64 + t] = av[i];
    }
}

// --- K1b: cself[t] = embed[nodeid] @ W1e[256:384,t] + b1e[t] ---
__global__ __launch_bounds__(64) void k_cself(const float* embed, const float* W1e,
                                              const float* b1e, const int* nodeid_p,
                                              float* cself) {
    __shared__ float emb[DIM];
    int t = threadIdx.x;
    int nodeid = nodeid_p[0];
    for (int i = t; i < DIM; i += 64) emb[i] = embed[(size_t)nodeid * DIM + i];
    __syncthreads();
    float a = b1e[t];
    for (int d = 0; d < DIM; d++) a += emb[d] * W1e[(2 * DIM + d) * 64 + t];
    cself[t] = a;
}

// --- Kxw: xw = x @ Wg0  [N,128] ---
__global__ __launch_bounds__(128) void k_xw(const float* x, const float* Wg0, float* xw) {
    __shared__ float xs[8][DIM];
    int t = threadIdx.x;
    int n0 = blockIdx.x * 8;
    for (int i = t; i < 8 * DIM; i += 128)
        xs[i / DIM][i % DIM] = x[(size_t)(n0 + i / DIM) * DIM + (i % DIM)];
    __syncthreads();
    float acc[8] = {0};
    for (int d = 0; d < DIM; d++) {
        float w = Wg0[d * DIM + t];
#pragma unroll
        for (int i = 0; i < 8; i++) acc[i] += xs[i][d] * w;
    }
    for (int i = 0; i < 8; i++) xw[(size_t)(n0 + i) * DIM + t] = acc[i];
}

// --- K2: per-edge gate values (wave per edge) ---
__global__ __launch_bounds__(256) void k_gates(const void* rowp, const void* colp,
        const float* noise, const float* U, const float* V, const float* cself,
        const float* W2e, const float* b2e, const float* tmp, const int* flags,
        float* values, int E) {
    int idx64 = flags[0];
    int wave = threadIdx.x >> 6;
    int lane = threadIdx.x & 63;
    int gw = blockIdx.x * 4 + wave;
    int nw = gridDim.x * 4;
    float w2 = W2e[lane];
    float cs = cself[lane];
    float beta = tmp[0];
    float b2 = b2e[0];
    for (int e = gw; e < E; e += nw) {
        int r = edge_idx(rowp, e, idx64);
        int c = edge_idx(colp, e, idx64);
        float h = U[(size_t)r * 64 + lane] + V[(size_t)c * 64 + lane] + cs;
        h = h > 0.f ? h : 0.f;
        float p = h * w2;
        for (int o = 32; o >= 1; o >>= 1) p += __shfl_xor(p, o, 64);
        if (lane == 0) {
            float la = p + b2;
            float nz = noise[e];
            float gi = (logf(nz) - log1pf(-nz) + la) / beta;
            values[e] = 1.f / (1.f + expf(-gi));
        }
    }
}

// --- K3: scan edges touching nodeid: cnt0/f0 (row==nodeid), r0 (col==nodeid) ---
__global__ void k_scan0(const void* rowp, const void* colp, const float* adj_data,
        const float* values, const int* nodeid_p, const int* flags,
        float* cnt0, float* f0, float* r0, int E) {
    int idx64 = flags[0];
    int nodeid = nodeid_p[0];
    int i = blockIdx.x * blockDim.x + threadIdx.x;
    int stride = gridDim.x * blockDim.x;
    for (int e = i; e < E; e += stride) {
        int r = edge_idx(rowp, e, idx64);
        int c = edge_idx(colp, e, idx64);
        if (r == c) continue;                      // diagonal is zeroed anyway
        if (r == nodeid) { atomicAdd(&cnt0[c], adj_data[e]); atomicAdd(&f0[c], values[e]); }
        if (c == nodeid) { atomicAdd(&r0[r], values[e]); }
    }
}

// --- K4: compact out-neighbors of nodeid into slots; A0c = masked_adj[nodeid, nbr] ---
__global__ void k_compact(const int* nodeid_p, const float* cnt0, const float* f0,
        const float* r0, int* flags, int* nbr, int* slotmap, float* A0c) {
    int nodeid = nodeid_p[0];
    int n = blockIdx.x * blockDim.x + threadIdx.x;
    if (n >= NNODES) return;
    int sm = -1;
    if (n != nodeid && cnt0[n] > 0.f) {
        int s = atomicAdd(&flags[1], 1);
        if (s < SMAX) {
            nbr[s] = n;
            A0c[s] = cnt0[n] * (f0[n] + r0[n]) * 0.5f;
            sm = s;
        }
    }
    slotmap[n] = sm;
}

// --- K5: pair-aggregate rows of masked_adj for each neighbor slot ---
__global__ void k_scan1(const void* rowp, const void* colp, const float* adj_data,
        const float* values, const int* slotmap, const int* flags,
        float* cntA, float* sumF, float* sumR, int E) {
    int idx64 = flags[0];
    int i = blockIdx.x * blockDim.x + threadIdx.x;
    int stride = gridDim.x * blockDim.x;
    for (int e = i; e < E; e += stride) {
        int r = edge_idx(rowp, e, idx64);
        int c = edge_idx(colp, e, idx64);
        if (r == c) continue;
        int s = slotmap[r];
        if (s >= 0) {
            atomicAdd(&cntA[(size_t)s * NNODES + c], adj_data[e]);
            atomicAdd(&sumF[(size_t)s * NNODES + c], values[e]);
        }
        int s2 = slotmap[c];
        if (s2 >= 0) atomicAdd(&sumR[(size_t)s2 * NNODES + r], values[e]);
    }
}

// --- K6: h1[s] = relu( sum_k masked_adj[nbr[s],k] * xw[k] )  (block per slot) ---
__global__ __launch_bounds__(128) void k_h1(const int* flags, const float* cntA,
        const float* sumF, const float* sumR, const float* xw, float* h1) {
    int s = blockIdx.x;
    int ns = flags[1]; if (ns > SMAX) ns = SMAX;
    if (s >= ns) return;
    int t = threadIdx.x;
    __shared__ int lk[128];
    __shared__ float lw[128];
    __shared__ int lcount;
    float acc = 0.f;
    for (int base = 0; base < NNODES; base += 128) {
        if (t == 0) lcount = 0;
        __syncthreads();
        int k = base + t;
        float cv = cntA[(size_t)s * NNODES + k];
        if (cv != 0.f) {
            int pos = atomicAdd(&lcount, 1);
            lk[pos] = k;
            lw[pos] = cv * (sumF[(size_t)s * NNODES + k] + sumR[(size_t)s * NNODES + k]) * 0.5f;
        }
        __syncthreads();
        int cnt = lcount;
        for (int i = 0; i < cnt; i++)
            acc += lw[i] * xw[(size_t)lk[i] * DIM + t];
        __syncthreads();
    }
    h1[(size_t)s * DIM + t] = acc > 0.f ? acc : 0.f;
}

// --- K7: out[c] = softmax_c( sum_s A0c[s] * (h1[s] @ Wg1)[c] ) ---
__global__ __launch_bounds__(256) void k_final(const int* flags, const float* h1,
        const float* A0c, const float* Wg1, float* out) {
    __shared__ float sacc[7];
    int t = threadIdx.x;
    if (t < 7) sacc[t] = 0.f;
    __syncthreads();
    int ns = flags[1]; if (ns > SMAX) ns = SMAX;
    int wave = t >> 6, lane = t & 63;
    for (int s = wave; s < ns; s += 4) {
        float a0 = A0c[s];
        float v0 = h1[(size_t)s * DIM + lane];
        float v1 = h1[(size_t)s * DIM + lane + 64];
        float part[7];
        for (int c = 0; c < 7; c++) {
            float p = v0 * Wg1[lane * 7 + c] + v1 * Wg1[(lane + 64) * 7 + c];
            for (int o = 32; o >= 1; o >>= 1) p += __shfl_xor(p, o, 64);
            part[c] = p;
        }
        if (lane == 0)
            for (int c = 0; c < 7; c++) atomicAdd(&sacc[c], a0 * part[c]);
    }
    __syncthreads();
    if (t == 0) {
        float v[7], m = -1e30f, ssum = 0.f;
        for (int c = 0; c < 7; c++) { v[c] = sacc[c]; if (v[c] > m) m = v[c]; }
        for (int c = 0; c < 7; c++) { v[c] = expf(v[c] - m); ssum += v[c]; }
        for (int c = 0; c < 7; c++) out[c] = v[c] / ssum;
    }
}

extern "C" void kernel_launch(void* const* d_in, const int* in_sizes, int n_in,
                              void* d_out, int out_size, void* d_ws, size_t ws_size,
                              hipStream_t stream) {
    const float* x     = (const float*)d_in[0];
    const float* embed = (const float*)d_in[1];
    const float* adjd  = (const float*)d_in[2];
    const float* noise = (const float*)d_in[3];
    const float* tmp   = (const float*)d_in[4];
    const float* W1e   = (const float*)d_in[5];
    const float* b1e   = (const float*)d_in[6];
    const float* W2e   = (const float*)d_in[7];
    const float* b2e   = (const float*)d_in[8];
    const float* Wg0   = (const float*)d_in[9];
    const float* Wg1   = (const float*)d_in[10];
    const void*  rowp  = d_in[11];
    const void*  colp  = d_in[12];
    const int*   nodep = (const int*)d_in[13];
    int E = in_sizes[3];   // noise is float32[E] regardless of index dtype

    char* w = (char*)d_ws;
    size_t off = 0;
    auto alloc = [&](size_t bytes) -> char* {
        char* p = w + off;
        off = (off + bytes + 255) & ~(size_t)255;
        return p;
    };
    int*   flags   = (int*)  alloc(16);
    float* cself   = (float*)alloc(64 * 4);
    float* A0c     = (float*)alloc(SMAX * 4);
    int*   nbr     = (int*)  alloc(SMAX * 4);
    int*   slotmap = (int*)  alloc((size_t)NNODES * 4);
    float* h1      = (float*)alloc((size_t)SMAX * DIM * 4);
    float* U       = (float*)alloc((size_t)NNODES * 64 * 4);
    float* V       = (float*)alloc((size_t)NNODES * 64 * 4);
    float* xw      = (float*)alloc((size_t)NNODES * DIM * 4);
    float* values  = (float*)alloc((size_t)E * 4);
    char*  zstart  = w + off;
    float* cnt0    = (float*)alloc((size_t)NNODES * 4);
    float* f0      = (float*)alloc((size_t)NNODES * 4);
    float* r0      = (float*)alloc((size_t)NNODES * 4);
    float* cntA    = (float*)alloc((size_t)SMAX * NNODES * 4);
    float* sumF    = (float*)alloc((size_t)SMAX * NNODES * 4);
    float* sumR    = (float*)alloc((size_t)SMAX * NNODES * 4);
    size_t zbytes  = (size_t)((w + off) - zstart);

    hipMemsetAsync(zstart, 0, zbytes, stream);
    k0_detect<<<1, 64, 0, stream>>>(rowp, flags);
    k_uv<<<NNODES / 8, 64, 0, stream>>>(embed, W1e, U, V);
    k_cself<<<1, 64, 0, stream>>>(embed, W1e, b1e, nodep, cself);
    k_xw<<<NNODES / 8, 128, 0, stream>>>(x, Wg0, xw);
    k_gates<<<2048, 256, 0, stream>>>(rowp, colp, noise, U, V, cself, W2e, b2e, tmp,
                                      flags, values, E);
    k_scan0<<<1024, 256, 0, stream>>>(rowp, colp, adjd, values, nodep, flags,
                                      cnt0, f0, r0, E);
    k_compact<<<NNODES / 256, 256, 0, stream>>>(nodep, cnt0, f0, r0, flags, nbr,
                                                slotmap, A0c);
    k_scan1<<<1024, 256, 0, stream>>>(rowp, colp, adjd, values, slotmap, flags,
                                      cntA, sumF, sumR, E);
    k_h1<<<SMAX, 128, 0, stream>>>(flags, cntA, sumF, sumR, xw, h1);
    k_final<<<1, 256, 0, stream>>>(flags, h1, A0c, Wg1, (float*)d_out);
}

// Round 2
// 117.704 us; speedup vs baseline: 1.7128x; 1.7128x over previous
//
#include <hip/hip_runtime.h>
#include <hip/hip_bf16.h>
#include <math.h>

#define NNODES 8192
#define DIM 128
#define SMAX 128

__device__ __forceinline__ int edge_idx(const void* p, int e, int idx64) {
    if (idx64) return (int)((const long long*)p)[e];
    return ((const int*)p)[e];
}

// --- K0: detect index dtype (int32 vs int64) + zero counters ---
__global__ void k0_detect(const void* rowp, int* flags) {
    if (threadIdx.x == 0 && blockIdx.x == 0) {
        const long long* p = (const long long*)rowp;
        int is64 = 1;
        for (int i = 0; i < 4; i++) {
            long long v = p[i];
            if (v < 0 || v >= NNODES) is64 = 0;
        }
        flags[0] = is64;
        flags[1] = 0;   // ns (neighbor slot counter)
        flags[2] = 0;   // edge list counter
    }
}

// --- K1a: U = embed @ W1e[0:128], V = embed @ W1e[128:256] ---
__global__ __launch_bounds__(64) void k_uv(const float* embed, const float* W1e,
                                           float* U, float* V) {
    __shared__ float emb[8][DIM];
    int t = threadIdx.x;
    int n0 = blockIdx.x * 8;
    for (int i = t; i < 8 * DIM; i += 64)
        emb[i / DIM][i % DIM] = embed[(size_t)(n0 + i / DIM) * DIM + (i % DIM)];
    __syncthreads();
    float au[8] = {0}, av[8] = {0};
    for (int d = 0; d < DIM; d++) {
        float w1 = W1e[d * 64 + t];
        float w2 = W1e[(DIM + d) * 64 + t];
#pragma unroll
        for (int i = 0; i < 8; i++) { au[i] += emb[i][d] * w1; av[i] += emb[i][d] * w2; }
    }
    for (int i = 0; i < 8; i++) {
        U[(size_t)(n0 + i) * 64 + t] = au[i];
        V[(size_t)(n0 + i) * 64 + t] = av[i];
    }
}

// --- K1b: cself[t] = embed[nodeid] @ W1e[256:384,t] + b1e[t] ---
__global__ __launch_bounds__(64) void k_cself(const float* embed, const float* W1e,
                                              const float* b1e, const int* nodeid_p,
                                              float* cself) {
    __shared__ float emb[DIM];
    int t = threadIdx.x;
    int nodeid = nodeid_p[0];
    for (int i = t; i < DIM; i += 64) emb[i] = embed[(size_t)nodeid * DIM + i];
    __syncthreads();
    float a = b1e[t];
    for (int d = 0; d < DIM; d++) a += emb[d] * W1e[(2 * DIM + d) * 64 + t];
    cself[t] = a;
}

// --- Kxw: xw = x @ Wg0  [N,128] ---
__global__ __launch_bounds__(128) void k_xw(const float* x, const float* Wg0, float* xw) {
    __shared__ float xs[8][DIM];
    int t = threadIdx.x;
    int n0 = blockIdx.x * 8;
    for (int i = t; i < 8 * DIM; i += 128)
        xs[i / DIM][i % DIM] = x[(size_t)(n0 + i / DIM) * DIM + (i % DIM)];
    __syncthreads();
    float acc[8] = {0};
    for (int d = 0; d < DIM; d++) {
        float w = Wg0[d * DIM + t];
#pragma unroll
        for (int i = 0; i < 8; i++) acc[i] += xs[i][d] * w;
    }
    for (int i = 0; i < 8; i++) xw[(size_t)(n0 + i) * DIM + t] = acc[i];
}

// --- K2: mark out-neighbors of nodeid: cnt0[c] = sum adj_data over edges nodeid->c ---
__global__ void k_scan_mark(const void* rowp, const void* colp, const float* adj_data,
        const int* nodeid_p, const int* flags, float* cnt0, int E) {
    int idx64 = flags[0];
    int nodeid = nodeid_p[0];
    int i = blockIdx.x * blockDim.x + threadIdx.x;
    int stride = gridDim.x * blockDim.x;
    for (int e = i; e < E; e += stride) {
        int r = edge_idx(rowp, e, idx64);
        if (r != nodeid) continue;
        int c = edge_idx(colp, e, idx64);
        if (c == nodeid) continue;                 // diagonal zeroed
        atomicAdd(&cnt0[c], adj_data[e]);
    }
}

// --- K3: compact neighbors into slots ---
__global__ void k_compact(const int* nodeid_p, const float* cnt0, int* flags,
                          int* slotmap, float* cnt0n) {
    int nodeid = nodeid_p[0];
    int n = blockIdx.x * blockDim.x + threadIdx.x;
    if (n >= NNODES) return;
    int sm = -1;
    if (n != nodeid && cnt0[n] > 0.f) {
        int s = atomicAdd(&flags[1], 1);
        if (s < SMAX) {
            cnt0n[s] = cnt0[n];
            sm = s;
        }
    }
    slotmap[n] = sm;
}

// --- K4: classify every edge; list the relevant ones; do value-free cntA adds ---
__global__ void k_scan_filter(const void* rowp, const void* colp, const float* adj_data,
        const int* nodeid_p, const int* slotmap, int* flags,
        unsigned int* list, float* cntA, int E) {
    int idx64 = flags[0];
    int nodeid = nodeid_p[0];
    int i = blockIdx.x * blockDim.x + threadIdx.x;
    int stride = gridDim.x * blockDim.x;
    for (int e = i; e < E; e += stride) {
        int r = edge_idx(rowp, e, idx64);
        int c = edge_idx(colp, e, idx64);
        if (r == c) continue;
        int sr = slotmap[r];
        int sc = slotmap[c];
        int f = 0;
        if (sr >= 0) { f |= 1; atomicAdd(&cntA[(size_t)sr * NNODES + c], adj_data[e]); }
        if (sc >= 0) f |= 2;
        if (r == nodeid && sc >= 0) f |= 4;
        if (c == nodeid && sr >= 0) f |= 8;
        if (f) {
            int pos = atomicAdd(&flags[2], 1);
            list[pos] = (unsigned int)e | ((unsigned int)f << 28);
        }
    }
}

// --- K5: gate MLP only for listed edges (wave per edge), scatter per flags ---
__global__ __launch_bounds__(256) void k_gates_list(const void* rowp, const void* colp,
        const unsigned int* list, const float* noise, const float* U, const float* V,
        const float* cself, const float* W2e, const float* b2e, const float* tmp,
        const int* flags, const int* slotmap,
        float* sumF, float* sumR, float* f0s, float* r0s) {
    int idx64 = flags[0];
    int ncnt = flags[2];
    int wave = threadIdx.x >> 6;
    int lane = threadIdx.x & 63;
    int gw = blockIdx.x * 4 + wave;
    int nw = gridDim.x * 4;
    float w2 = W2e[lane];
    float cs = cself[lane];
    float beta = tmp[0];
    float b2 = b2e[0];
    for (int i = gw; i < ncnt; i += nw) {
        unsigned int u = list[i];
        int e = (int)(u & 0x0FFFFFFFu);
        int f = (int)(u >> 28);
        int r = edge_idx(rowp, e, idx64);
        int c = edge_idx(colp, e, idx64);
        float h = U[(size_t)r * 64 + lane] + V[(size_t)c * 64 + lane] + cs;
        h = h > 0.f ? h : 0.f;
        float p = h * w2;
        for (int o = 32; o >= 1; o >>= 1) p += __shfl_xor(p, o, 64);
        if (lane == 0) {
            float la = p + b2;
            float nz = noise[e];
            float gi = (logf(nz) - log1pf(-nz) + la) / beta;
            float v = 1.f / (1.f + expf(-gi));
            if (f & 1) atomicAdd(&sumF[(size_t)slotmap[r] * NNODES + c], v);
            if (f & 2) atomicAdd(&sumR[(size_t)slotmap[c] * NNODES + r], v);
            if (f & 4) atomicAdd(&f0s[slotmap[c]], v);
            if (f & 8) atomicAdd(&r0s[slotmap[r]], v);
        }
    }
}

// --- K6: h1[s] = relu( sum_k masked_adj[nbr[s],k] * xw[k] )  (block per slot) ---
__global__ __launch_bounds__(128) void k_h1(const int* flags, const float* cntA,
        const float* sumF, const float* sumR, const float* xw, float* h1) {
    int s = blockIdx.x;
    int ns = flags[1]; if (ns > SMAX) ns = SMAX;
    if (s >= ns) return;
    int t = threadIdx.x;
    __shared__ int lk[128];
    __shared__ float lw[128];
    __shared__ int lcount;
    float acc = 0.f;
    for (int base = 0; base < NNODES; base += 128) {
        if (t == 0) lcount = 0;
        __syncthreads();
        int k = base + t;
        float cv = cntA[(size_t)s * NNODES + k];
        if (cv != 0.f) {
            int pos = atomicAdd(&lcount, 1);
            lk[pos] = k;
            lw[pos] = cv * (sumF[(size_t)s * NNODES + k] + sumR[(size_t)s * NNODES + k]) * 0.5f;
        }
        __syncthreads();
        int cnt = lcount;
        for (int i = 0; i < cnt; i++)
            acc += lw[i] * xw[(size_t)lk[i] * DIM + t];
        __syncthreads();
    }
    h1[(size_t)s * DIM + t] = acc > 0.f ? acc : 0.f;
}

// --- K7: out = softmax( sum_s A0c[s] * (h1[s] @ Wg1) ), A0c computed inline ---
__global__ __launch_bounds__(256) void k_final(const int* flags, const float* h1,
        const float* cnt0n, const float* f0s, const float* r0s,
        const float* Wg1, float* out) {
    __shared__ float sacc[7];
    int t = threadIdx.x;
    if (t < 7) sacc[t] = 0.f;
    __syncthreads();
    int ns = flags[1]; if (ns > SMAX) ns = SMAX;
    int wave = t >> 6, lane = t & 63;
    for (int s = wave; s < ns; s += 4) {
        float a0 = cnt0n[s] * (f0s[s] + r0s[s]) * 0.5f;
        float v0 = h1[(size_t)s * DIM + lane];
        float v1 = h1[(size_t)s * DIM + lane + 64];
        float part[7];
        for (int c = 0; c < 7; c++) {
            float p = v0 * Wg1[lane * 7 + c] + v1 * Wg1[(lane + 64) * 7 + c];
            for (int o = 32; o >= 1; o >>= 1) p += __shfl_xor(p, o, 64);
            part[c] = p;
        }
        if (lane == 0)
            for (int c = 0; c < 7; c++) atomicAdd(&sacc[c], a0 * part[c]);
    }
    __syncthreads();
    if (t == 0) {
        float v[7], m = -1e30f, ssum = 0.f;
        for (int c = 0; c < 7; c++) { v[c] = sacc[c]; if (v[c] > m) m = v[c]; }
        for (int c = 0; c < 7; c++) { v[c] = expf(v[c] - m); ssum += v[c]; }
        for (int c = 0; c < 7; c++) out[c] = v[c] / ssum;
    }
}

extern "C" void kernel_launch(void* const* d_in, const int* in_sizes, int n_in,
                              void* d_out, int out_size, void* d_ws, size_t ws_size,
                              hipStream_t stream) {
    const float* x     = (const float*)d_in[0];
    const float* embed = (const float*)d_in[1];
    const float* adjd  = (const float*)d_in[2];
    const float* noise = (const float*)d_in[3];
    const float* tmp   = (const float*)d_in[4];
    const float* W1e   = (const float*)d_in[5];
    const float* b1e   = (const float*)d_in[6];
    const float* W2e   = (const float*)d_in[7];
    const float* b2e   = (const float*)d_in[8];
    const float* Wg0   = (const float*)d_in[9];
    const float* Wg1   = (const float*)d_in[10];
    const void*  rowp  = d_in[11];
    const void*  colp  = d_in[12];
    const int*   nodep = (const int*)d_in[13];
    int E = in_sizes[3];   // noise is float32[E]

    char* w = (char*)d_ws;
    size_t off = 0;
    auto alloc = [&](size_t bytes) -> char* {
        char* p = w + off;
        off = (off + bytes + 255) & ~(size_t)255;
        return p;
    };
    int*          flags   = (int*)  alloc(16);
    float*        cself   = (float*)alloc(64 * 4);
    float*        cnt0n   = (float*)alloc(SMAX * 4);
    int*          slotmap = (int*)  alloc((size_t)NNODES * 4);
    float*        h1      = (float*)alloc((size_t)SMAX * DIM * 4);
    float*        U       = (float*)alloc((size_t)NNODES * 64 * 4);
    float*        V       = (float*)alloc((size_t)NNODES * 64 * 4);
    float*        xw      = (float*)alloc((size_t)NNODES * DIM * 4);
    unsigned int* list    = (unsigned int*)alloc((size_t)E * 4);
    char*         zstart  = w + off;
    float*        cnt0    = (float*)alloc((size_t)NNODES * 4);
    float*        f0s     = (float*)alloc(SMAX * 4);
    float*        r0s     = (float*)alloc(SMAX * 4);
    float*        cntA    = (float*)alloc((size_t)SMAX * NNODES * 4);
    float*        sumF    = (float*)alloc((size_t)SMAX * NNODES * 4);
    float*        sumR    = (float*)alloc((size_t)SMAX * NNODES * 4);
    size_t zbytes  = (size_t)((w + off) - zstart);

    hipMemsetAsync(zstart, 0, zbytes, stream);
    k0_detect<<<1, 64, 0, stream>>>(rowp, flags);
    k_uv<<<NNODES / 8, 64, 0, stream>>>(embed, W1e, U, V);
    k_cself<<<1, 64, 0, stream>>>(embed, W1e, b1e, nodep, cself);
    k_xw<<<NNODES / 8, 128, 0, stream>>>(x, Wg0, xw);
    k_scan_mark<<<1024, 256, 0, stream>>>(rowp, colp, adjd, nodep, flags, cnt0, E);
    k_compact<<<NNODES / 256, 256, 0, stream>>>(nodep, cnt0, flags, slotmap, cnt0n);
    k_scan_filter<<<1024, 256, 0, stream>>>(rowp, colp, adjd, nodep, slotmap, flags,
                                            list, cntA, E);
    k_gates_list<<<512, 256, 0, stream>>>(rowp, colp, list, noise, U, V, cself,
                                          W2e, b2e, tmp, flags, slotmap,
                                          sumF, sumR, f0s, r0s);
    k_h1<<<SMAX, 128, 0, stream>>>(flags, cntA, sumF, sumR, xw, h1);
    k_final<<<1, 256, 0, stream>>>(flags, h1, cnt0n, f0s, r0s, Wg1, (float*)d_out);
}

// Round 3
// 82.343 us; speedup vs baseline: 2.4483x; 1.4294x over previous
//
#include <hip/hip_runtime.h>
#include <hip/hip_bf16.h>
#include <math.h>

#define NNODES 8192
#define DIM 128
#define SMAX 128
#define HSIZE 16384   // hash table capacity (power of 2)

__device__ __forceinline__ int edge_idx(const void* p, int e, int idx64) {
    if (idx64) return (int)((const long long*)p)[e];
    return ((const int*)p)[e];
}

__device__ __forceinline__ int hash_insert(unsigned int* hashK, unsigned int key1) {
    unsigned int h = (key1 * 2654435761u) & (HSIZE - 1);
    for (;;) {
        unsigned int prev = atomicCAS(&hashK[h], 0u, key1);
        if (prev == 0u || prev == key1) return (int)h;
        h = (h + 1) & (HSIZE - 1);
    }
}

__device__ __forceinline__ int hash_find(const unsigned int* hashK, unsigned int key1) {
    unsigned int h = (key1 * 2654435761u) & (HSIZE - 1);
    for (;;) {
        unsigned int k = hashK[h];
        if (k == key1) return (int)h;
        h = (h + 1) & (HSIZE - 1);
    }
}

// --- K0: detect index dtype (int32 vs int64) + zero counters ---
__global__ void k0_detect(const void* rowp, int* flags) {
    if (threadIdx.x == 0 && blockIdx.x == 0) {
        const long long* p = (const long long*)rowp;
        int is64 = 1;
        for (int i = 0; i < 4; i++) {
            long long v = p[i];
            if (v < 0 || v >= NNODES) is64 = 0;
        }
        flags[0] = is64;
        flags[1] = 0;   // ns (neighbor slot counter)
        flags[2] = 0;   // edge list counter
    }
}

// --- K1a: U = embed @ W1e[0:128], V = embed @ W1e[128:256] ---
__global__ __launch_bounds__(64) void k_uv(const float* embed, const float* W1e,
                                           float* U, float* V) {
    __shared__ float emb[8][DIM];
    int t = threadIdx.x;
    int n0 = blockIdx.x * 8;
    for (int i = t; i < 8 * DIM; i += 64)
        emb[i / DIM][i % DIM] = embed[(size_t)(n0 + i / DIM) * DIM + (i % DIM)];
    __syncthreads();
    float au[8] = {0}, av[8] = {0};
    for (int d = 0; d < DIM; d++) {
        float w1 = W1e[d * 64 + t];
        float w2 = W1e[(DIM + d) * 64 + t];
#pragma unroll
        for (int i = 0; i < 8; i++) { au[i] += emb[i][d] * w1; av[i] += emb[i][d] * w2; }
    }
    for (int i = 0; i < 8; i++) {
        U[(size_t)(n0 + i) * 64 + t] = au[i];
        V[(size_t)(n0 + i) * 64 + t] = av[i];
    }
}

// --- K1b: cself[t] = embed[nodeid] @ W1e[256:384,t] + b1e[t] ---
__global__ __launch_bounds__(64) void k_cself(const float* embed, const float* W1e,
                                              const float* b1e, const int* nodeid_p,
                                              float* cself) {
    __shared__ float emb[DIM];
    int t = threadIdx.x;
    int nodeid = nodeid_p[0];
    for (int i = t; i < DIM; i += 64) emb[i] = embed[(size_t)nodeid * DIM + i];
    __syncthreads();
    float a = b1e[t];
    for (int d = 0; d < DIM; d++) a += emb[d] * W1e[(2 * DIM + d) * 64 + t];
    cself[t] = a;
}

// --- Kxw: xw = x @ Wg0  [N,128] ---
__global__ __launch_bounds__(128) void k_xw(const float* x, const float* Wg0, float* xw) {
    __shared__ float xs[8][DIM];
    int t = threadIdx.x;
    int n0 = blockIdx.x * 8;
    for (int i = t; i < 8 * DIM; i += 128)
        xs[i / DIM][i % DIM] = x[(size_t)(n0 + i / DIM) * DIM + (i % DIM)];
    __syncthreads();
    float acc[8] = {0};
    for (int d = 0; d < DIM; d++) {
        float w = Wg0[d * DIM + t];
#pragma unroll
        for (int i = 0; i < 8; i++) acc[i] += xs[i][d] * w;
    }
    for (int i = 0; i < 8; i++) xw[(size_t)(n0 + i) * DIM + t] = acc[i];
}

// --- K2: mark out-neighbors of nodeid: cnt0[c] = sum adj_data over edges nodeid->c ---
__global__ void k_scan_mark(const void* rowp, const void* colp, const float* adj_data,
        const int* nodeid_p, const int* flags, float* cnt0, int E) {
    int idx64 = flags[0];
    int nodeid = nodeid_p[0];
    int i = blockIdx.x * blockDim.x + threadIdx.x;
    int stride = gridDim.x * blockDim.x;
    for (int e = i; e < E; e += stride) {
        int r = edge_idx(rowp, e, idx64);
        if (r != nodeid) continue;
        int c = edge_idx(colp, e, idx64);
        if (c == nodeid) continue;                 // diagonal zeroed
        atomicAdd(&cnt0[c], adj_data[e]);
    }
}

// --- K3: compact neighbors into slots ---
__global__ void k_compact(const int* nodeid_p, const float* cnt0, int* flags,
                          int* slotmap, float* cnt0n) {
    int nodeid = nodeid_p[0];
    int n = blockIdx.x * blockDim.x + threadIdx.x;
    if (n >= NNODES) return;
    int sm = -1;
    if (n != nodeid && cnt0[n] > 0.f) {
        int s = atomicAdd(&flags[1], 1);
        if (s < SMAX) {
            cnt0n[s] = cnt0[n];
            sm = s;
        }
    }
    slotmap[n] = sm;
}

// --- K4: classify every edge; list relevant ones; hash-insert + cnt adds ---
__global__ void k_scan_filter(const void* rowp, const void* colp, const float* adj_data,
        const int* nodeid_p, const int* slotmap, int* flags,
        unsigned int* list, unsigned int* hashK, float* hashC, int E) {
    int idx64 = flags[0];
    int nodeid = nodeid_p[0];
    int i = blockIdx.x * blockDim.x + threadIdx.x;
    int stride = gridDim.x * blockDim.x;
    for (int e = i; e < E; e += stride) {
        int r = edge_idx(rowp, e, idx64);
        int c = edge_idx(colp, e, idx64);
        if (r == c) continue;
        int sr = slotmap[r];
        int sc = slotmap[c];
        int f = 0;
        if (sr >= 0) {
            f |= 1;
            unsigned int key1 = ((unsigned int)(sr << 13) | (unsigned int)c) + 1u;
            int idx = hash_insert(hashK, key1);
            atomicAdd(&hashC[idx], adj_data[e]);
        }
        if (sc >= 0) {
            f |= 2;
            unsigned int key1 = ((unsigned int)(sc << 13) | (unsigned int)r) + 1u;
            hash_insert(hashK, key1);   // ensure entry exists for sumR scatter
        }
        if (r == nodeid && sc >= 0) f |= 4;
        if (c == nodeid && sr >= 0) f |= 8;
        if (f) {
            int pos = atomicAdd(&flags[2], 1);
            list[pos] = (unsigned int)e | ((unsigned int)f << 28);
        }
    }
}

// --- K5: gate MLP only for listed edges (wave per edge), scatter per flags ---
__global__ __launch_bounds__(256) void k_gates_list(const void* rowp, const void* colp,
        const unsigned int* list, const float* noise, const float* U, const float* V,
        const float* cself, const float* W2e, const float* b2e, const float* tmp,
        const int* flags, const int* slotmap, const unsigned int* hashK,
        float* hashF, float* hashR, float* f0s, float* r0s) {
    int idx64 = flags[0];
    int ncnt = flags[2];
    int wave = threadIdx.x >> 6;
    int lane = threadIdx.x & 63;
    int gw = blockIdx.x * 4 + wave;
    int nw = gridDim.x * 4;
    float w2 = W2e[lane];
    float cs = cself[lane];
    float beta = tmp[0];
    float b2 = b2e[0];
    for (int i = gw; i < ncnt; i += nw) {
        unsigned int u = list[i];
        int e = (int)(u & 0x0FFFFFFFu);
        int f = (int)(u >> 28);
        int r = edge_idx(rowp, e, idx64);
        int c = edge_idx(colp, e, idx64);
        float h = U[(size_t)r * 64 + lane] + V[(size_t)c * 64 + lane] + cs;
        h = h > 0.f ? h : 0.f;
        float p = h * w2;
        for (int o = 32; o >= 1; o >>= 1) p += __shfl_xor(p, o, 64);
        if (lane == 0) {
            float la = p + b2;
            float nz = noise[e];
            float gi = (logf(nz) - log1pf(-nz) + la) / beta;
            float v = 1.f / (1.f + expf(-gi));
            if (f & 1) {
                unsigned int key1 = ((unsigned int)(slotmap[r] << 13) | (unsigned int)c) + 1u;
                atomicAdd(&hashF[hash_find(hashK, key1)], v);
            }
            if (f & 2) {
                unsigned int key1 = ((unsigned int)(slotmap[c] << 13) | (unsigned int)r) + 1u;
                atomicAdd(&hashR[hash_find(hashK, key1)], v);
            }
            if (f & 4) atomicAdd(&f0s[slotmap[c]], v);
            if (f & 8) atomicAdd(&r0s[slotmap[r]], v);
        }
    }
}

// --- K6: per hash entry, h1acc[s][:] += cnt*(sF+sR)/2 * xw[k][:] ---
__global__ __launch_bounds__(256) void k_hagg(const unsigned int* hashK,
        const float* hashC, const float* hashF, const float* hashR,
        const float* xw, float* h1acc) {
    int entry = blockIdx.x * 2 + (threadIdx.x >> 7);
    int t = threadIdx.x & 127;
    unsigned int key1 = hashK[entry];
    if (key1 == 0u) return;
    float w = hashC[entry] * (hashF[entry] + hashR[entry]) * 0.5f;
    if (w == 0.f) return;
    unsigned int key = key1 - 1u;
    int s = (int)(key >> 13);
    int k = (int)(key & 8191u);
    atomicAdd(&h1acc[(size_t)s * DIM + t], w * xw[(size_t)k * DIM + t]);
}

// --- K7: out = softmax( sum_s A0c[s] * (relu(h1acc[s]) @ Wg1) ) ---
__global__ __launch_bounds__(256) void k_final(const int* flags, const float* h1acc,
        const float* cnt0n, const float* f0s, const float* r0s,
        const float* Wg1, float* out) {
    __shared__ float sacc[7];
    int t = threadIdx.x;
    if (t < 7) sacc[t] = 0.f;
    __syncthreads();
    int ns = flags[1]; if (ns > SMAX) ns = SMAX;
    int wave = t >> 6, lane = t & 63;
    for (int s = wave; s < ns; s += 4) {
        float a0 = cnt0n[s] * (f0s[s] + r0s[s]) * 0.5f;
        float v0 = h1acc[(size_t)s * DIM + lane];
        float v1 = h1acc[(size_t)s * DIM + lane + 64];
        v0 = v0 > 0.f ? v0 : 0.f;
        v1 = v1 > 0.f ? v1 : 0.f;
        float part[7];
        for (int c = 0; c < 7; c++) {
            float p = v0 * Wg1[lane * 7 + c] + v1 * Wg1[(lane + 64) * 7 + c];
            for (int o = 32; o >= 1; o >>= 1) p += __shfl_xor(p, o, 64);
            part[c] = p;
        }
        if (lane == 0)
            for (int c = 0; c < 7; c++) atomicAdd(&sacc[c], a0 * part[c]);
    }
    __syncthreads();
    if (t == 0) {
        float v[7], m = -1e30f, ssum = 0.f;
        for (int c = 0; c < 7; c++) { v[c] = sacc[c]; if (v[c] > m) m = v[c]; }
        for (int c = 0; c < 7; c++) { v[c] = expf(v[c] - m); ssum += v[c]; }
        for (int c = 0; c < 7; c++) out[c] = v[c] / ssum;
    }
}

extern "C" void kernel_launch(void* const* d_in, const int* in_sizes, int n_in,
                              void* d_out, int out_size, void* d_ws, size_t ws_size,
                              hipStream_t stream) {
    const float* x     = (const float*)d_in[0];
    const float* embed = (const float*)d_in[1];
    const float* adjd  = (const float*)d_in[2];
    const float* noise = (const float*)d_in[3];
    const float* tmp   = (const float*)d_in[4];
    const float* W1e   = (const float*)d_in[5];
    const float* b1e   = (const float*)d_in[6];
    const float* W2e   = (const float*)d_in[7];
    const float* b2e   = (const float*)d_in[8];
    const float* Wg0   = (const float*)d_in[9];
    const float* Wg1   = (const float*)d_in[10];
    const void*  rowp  = d_in[11];
    const void*  colp  = d_in[12];
    const int*   nodep = (const int*)d_in[13];
    int E = in_sizes[3];   // noise is float32[E]

    char* w = (char*)d_ws;
    size_t off = 0;
    auto alloc = [&](size_t bytes) -> char* {
        char* p = w + off;
        off = (off + bytes + 255) & ~(size_t)255;
        return p;
    };
    int*          flags   = (int*)  alloc(16);
    float*        cself   = (float*)alloc(64 * 4);
    float*        cnt0n   = (float*)alloc(SMAX * 4);
    int*          slotmap = (int*)  alloc((size_t)NNODES * 4);
    float*        U       = (float*)alloc((size_t)NNODES * 64 * 4);
    float*        V       = (float*)alloc((size_t)NNODES * 64 * 4);
    float*        xw      = (float*)alloc((size_t)NNODES * DIM * 4);
    unsigned int* list    = (unsigned int*)alloc((size_t)E * 4);
    char*         zstart  = w + off;
    float*        cnt0    = (float*)alloc((size_t)NNODES * 4);
    float*        f0s     = (float*)alloc(SMAX * 4);
    float*        r0s     = (float*)alloc(SMAX * 4);
    unsigned int* hashK   = (unsigned int*)alloc((size_t)HSIZE * 4);
    float*        hashC   = (float*)alloc((size_t)HSIZE * 4);
    float*        hashF   = (float*)alloc((size_t)HSIZE * 4);
    float*        hashR   = (float*)alloc((size_t)HSIZE * 4);
    float*        h1acc   = (float*)alloc((size_t)SMAX * DIM * 4);
    size_t zbytes  = (size_t)((w + off) - zstart);

    hipMemsetAsync(zstart, 0, zbytes, stream);
    k0_detect<<<1, 64, 0, stream>>>(rowp, flags);
    k_uv<<<NNODES / 8, 64, 0, stream>>>(embed, W1e, U, V);
    k_cself<<<1, 64, 0, stream>>>(embed, W1e, b1e, nodep, cself);
    k_xw<<<NNODES / 8, 128, 0, stream>>>(x, Wg0, xw);
    k_scan_mark<<<1024, 256, 0, stream>>>(rowp, colp, adjd, nodep, flags, cnt0, E);
    k_compact<<<NNODES / 256, 256, 0, stream>>>(nodep, cnt0, flags, slotmap, cnt0n);
    k_scan_filter<<<1024, 256, 0, stream>>>(rowp, colp, adjd, nodep, slotmap, flags,
                                            list, hashK, hashC, E);
    k_gates_list<<<512, 256, 0, stream>>>(rowp, colp, list, noise, U, V, cself,
                                          W2e, b2e, tmp, flags, slotmap, hashK,
                                          hashF, hashR, f0s, r0s);
    k_hagg<<<HSIZE / 2, 256, 0, stream>>>(hashK, hashC, hashF, hashR, xw, h1acc);
    k_final<<<1, 256, 0, stream>>>(flags, h1acc, cnt0n, f0s, r0s, Wg1, (float*)d_out);
}

// Round 4
// 70.567 us; speedup vs baseline: 2.8569x; 1.1669x over previous
//
#include <hip/hip_runtime.h>
#include <hip/hip_bf16.h>
#include <math.h>

#define NNODES 8192
#define DIM 128
#define SMAX 128
#define HSIZE 16384   // hash table capacity (power of 2)

// Per-thread index-dtype detection: reads first 4 int64-interpretations of row.
// All < NNODES => data is int64 (false positive prob ~ (1/8192)^4 for int32 data).
__device__ __forceinline__ int detect64(const void* rowp) {
    const long long* p = (const long long*)rowp;
    int is64 = 1;
#pragma unroll
    for (int i = 0; i < 4; i++) {
        long long v = p[i];
        if (v < 0 || v >= NNODES) is64 = 0;
    }
    return is64;
}

__device__ __forceinline__ int edge_idx(const void* p, int e, int idx64) {
    if (idx64) return (int)((const long long*)p)[e];
    return ((const int*)p)[e];
}

__device__ __forceinline__ int hash_insert(unsigned int* hashK, unsigned int key1) {
    unsigned int h = (key1 * 2654435761u) & (HSIZE - 1);
    for (;;) {
        unsigned int prev = atomicCAS(&hashK[h], 0u, key1);
        if (prev == 0u || prev == key1) return (int)h;
        h = (h + 1) & (HSIZE - 1);
    }
}

__device__ __forceinline__ int hash_find(const unsigned int* hashK, unsigned int key1) {
    unsigned int h = (key1 * 2654435761u) & (HSIZE - 1);
    for (;;) {
        unsigned int k = hashK[h];
        if (k == key1) return (int)h;
        h = (h + 1) & (HSIZE - 1);
    }
}

// --- K0: zero the scratch region (custom: rocclr fillBuffer is 39us for 353KB) ---
__global__ __launch_bounds__(256) void k_zero(float4* z, int n4) {
    int i = blockIdx.x * blockDim.x + threadIdx.x;
    if (i < n4) z[i] = make_float4(0.f, 0.f, 0.f, 0.f);
}

// --- K1: fused dense precompute.
// blocks [0,1024):      U = embed @ W1e[0:128], V = embed @ W1e[128:256]
// blocks [1024,2048):   xw = x @ Wg0
// block  2048:          cself = embed[nodeid] @ W1e[256:384] + b1e
__global__ __launch_bounds__(128) void k_dense(const float* embed, const float* x,
        const float* W1e, const float* b1e, const float* Wg0, const int* nodeid_p,
        float* U, float* V, float* xw, float* cself) {
    __shared__ float sm[8][DIM];
    int b = blockIdx.x;
    int t = threadIdx.x;
    if (b < 1024) {
        int n0 = b * 8;
        for (int i = t; i < 8 * DIM; i += 128)
            sm[i / DIM][i % DIM] = embed[(size_t)(n0 + i / DIM) * DIM + (i % DIM)];
        __syncthreads();
        int half = t >> 6;           // 0 -> U, 1 -> V
        int lane = t & 63;
        const float* Wc = W1e + (size_t)half * DIM * 64;
        float acc[8] = {0};
        for (int d = 0; d < DIM; d++) {
            float w = Wc[d * 64 + lane];
#pragma unroll
            for (int i = 0; i < 8; i++) acc[i] += sm[i][d] * w;
        }
        float* out = half ? V : U;
        for (int i = 0; i < 8; i++) out[(size_t)(n0 + i) * 64 + lane] = acc[i];
    } else if (b < 2048) {
        int n0 = (b - 1024) * 8;
        for (int i = t; i < 8 * DIM; i += 128)
            sm[i / DIM][i % DIM] = x[(size_t)(n0 + i / DIM) * DIM + (i % DIM)];
        __syncthreads();
        float acc[8] = {0};
        for (int d = 0; d < DIM; d++) {
            float w = Wg0[d * DIM + t];
#pragma unroll
            for (int i = 0; i < 8; i++) acc[i] += sm[i][d] * w;
        }
        for (int i = 0; i < 8; i++) xw[(size_t)(n0 + i) * DIM + t] = acc[i];
    } else {
        int nodeid = nodeid_p[0];
        if (t < DIM) sm[0][t] = embed[(size_t)nodeid * DIM + t];
        __syncthreads();
        if (t < 64) {
            float a = b1e[t];
            for (int d = 0; d < DIM; d++) a += sm[0][d] * W1e[(2 * DIM + d) * 64 + t];
            cself[t] = a;
        }
    }
}

// --- K2: mark out-neighbors of nodeid: cnt0[c] = sum adj_data over edges nodeid->c ---
__global__ __launch_bounds__(256) void k_scan_mark(const void* rowp, const void* colp,
        const float* adj_data, const int* nodeid_p, float* cnt0, int E) {
    int idx64 = detect64(rowp);
    int nodeid = nodeid_p[0];
    int i = blockIdx.x * blockDim.x + threadIdx.x;
    int stride = gridDim.x * blockDim.x;
    for (int e = i; e < E; e += stride) {
        int r = edge_idx(rowp, e, idx64);
        if (r != nodeid) continue;
        int c = edge_idx(colp, e, idx64);
        if (c == nodeid) continue;                 // diagonal zeroed
        atomicAdd(&cnt0[c], adj_data[e]);
    }
}

// --- K3: compact neighbors into slots ---
__global__ __launch_bounds__(256) void k_compact(const int* nodeid_p, const float* cnt0,
        int* flags, int* slotmap, float* cnt0n) {
    int nodeid = nodeid_p[0];
    int n = blockIdx.x * blockDim.x + threadIdx.x;
    if (n >= NNODES) return;
    int sm = -1;
    if (n != nodeid && cnt0[n] > 0.f) {
        int s = atomicAdd(&flags[1], 1);
        if (s < SMAX) {
            cnt0n[s] = cnt0[n];
            sm = s;
        }
    }
    slotmap[n] = sm;
}

// --- K4: classify every edge; list relevant ones; hash-insert + cnt adds ---
__global__ __launch_bounds__(256) void k_scan_filter(const void* rowp, const void* colp,
        const float* adj_data, const int* nodeid_p, const int* slotmap, int* flags,
        unsigned int* list, unsigned int* hashK, float* hashC, int E) {
    int idx64 = detect64(rowp);
    int nodeid = nodeid_p[0];
    int i = blockIdx.x * blockDim.x + threadIdx.x;
    int stride = gridDim.x * blockDim.x;
    for (int e = i; e < E; e += stride) {
        int r = edge_idx(rowp, e, idx64);
        int c = edge_idx(colp, e, idx64);
        if (r == c) continue;
        int sr = slotmap[r];
        int sc = slotmap[c];
        int f = 0;
        if (sr >= 0) {
            f |= 1;
            unsigned int key1 = ((unsigned int)(sr << 13) | (unsigned int)c) + 1u;
            int idx = hash_insert(hashK, key1);
            atomicAdd(&hashC[idx], adj_data[e]);
        }
        if (sc >= 0) {
            f |= 2;
            unsigned int key1 = ((unsigned int)(sc << 13) | (unsigned int)r) + 1u;
            hash_insert(hashK, key1);   // ensure entry exists for sumR scatter
        }
        if (r == nodeid && sc >= 0) f |= 4;
        if (c == nodeid && sr >= 0) f |= 8;
        if (f) {
            int pos = atomicAdd(&flags[2], 1);
            list[pos] = (unsigned int)e | ((unsigned int)f << 28);
        }
    }
}

// --- K5: gate MLP only for listed edges (wave per edge), scatter per flags ---
__global__ __launch_bounds__(256) void k_gates_list(const void* rowp, const void* colp,
        const unsigned int* list, const float* noise, const float* U, const float* V,
        const float* cself, const float* W2e, const float* b2e, const float* tmp,
        const int* flags, const int* slotmap, const unsigned int* hashK,
        float* hashF, float* hashR, float* f0s, float* r0s) {
    int idx64 = detect64(rowp);
    int ncnt = flags[2];
    int wave = threadIdx.x >> 6;
    int lane = threadIdx.x & 63;
    int gw = blockIdx.x * 4 + wave;
    int nw = gridDim.x * 4;
    float w2 = W2e[lane];
    float cs = cself[lane];
    float beta = tmp[0];
    float b2 = b2e[0];
    for (int i = gw; i < ncnt; i += nw) {
        unsigned int u = list[i];
        int e = (int)(u & 0x0FFFFFFFu);
        int f = (int)(u >> 28);
        int r = edge_idx(rowp, e, idx64);
        int c = edge_idx(colp, e, idx64);
        float h = U[(size_t)r * 64 + lane] + V[(size_t)c * 64 + lane] + cs;
        h = h > 0.f ? h : 0.f;
        float p = h * w2;
        for (int o = 32; o >= 1; o >>= 1) p += __shfl_xor(p, o, 64);
        if (lane == 0) {
            float la = p + b2;
            float nz = noise[e];
            float gi = (logf(nz) - log1pf(-nz) + la) / beta;
            float v = 1.f / (1.f + expf(-gi));
            if (f & 1) {
                unsigned int key1 = ((unsigned int)(slotmap[r] << 13) | (unsigned int)c) + 1u;
                atomicAdd(&hashF[hash_find(hashK, key1)], v);
            }
            if (f & 2) {
                unsigned int key1 = ((unsigned int)(slotmap[c] << 13) | (unsigned int)r) + 1u;
                atomicAdd(&hashR[hash_find(hashK, key1)], v);
            }
            if (f & 4) atomicAdd(&f0s[slotmap[c]], v);
            if (f & 8) atomicAdd(&r0s[slotmap[r]], v);
        }
    }
}

// --- K6: per hash entry, h1acc[s][:] += cnt*(sF+sR)/2 * xw[k][:] ---
__global__ __launch_bounds__(256) void k_hagg(const unsigned int* hashK,
        const float* hashC, const float* hashF, const float* hashR,
        const float* xw, float* h1acc) {
    int entry = blockIdx.x * 2 + (threadIdx.x >> 7);
    int t = threadIdx.x & 127;
    unsigned int key1 = hashK[entry];
    if (key1 == 0u) return;
    float w = hashC[entry] * (hashF[entry] + hashR[entry]) * 0.5f;
    if (w == 0.f) return;
    unsigned int key = key1 - 1u;
    int s = (int)(key >> 13);
    int k = (int)(key & 8191u);
    atomicAdd(&h1acc[(size_t)s * DIM + t], w * xw[(size_t)k * DIM + t]);
}

// --- K7: out = softmax( sum_s A0c[s] * (relu(h1acc[s]) @ Wg1) ) ---
__global__ __launch_bounds__(256) void k_final(const int* flags, const float* h1acc,
        const float* cnt0n, const float* f0s, const float* r0s,
        const float* Wg1, float* out) {
    __shared__ float sacc[7];
    int t = threadIdx.x;
    if (t < 7) sacc[t] = 0.f;
    __syncthreads();
    int ns = flags[1]; if (ns > SMAX) ns = SMAX;
    int wave = t >> 6, lane = t & 63;
    for (int s = wave; s < ns; s += 4) {
        float a0 = cnt0n[s] * (f0s[s] + r0s[s]) * 0.5f;
        float v0 = h1acc[(size_t)s * DIM + lane];
        float v1 = h1acc[(size_t)s * DIM + lane + 64];
        v0 = v0 > 0.f ? v0 : 0.f;
        v1 = v1 > 0.f ? v1 : 0.f;
        float part[7];
        for (int c = 0; c < 7; c++) {
            float p = v0 * Wg1[lane * 7 + c] + v1 * Wg1[(lane + 64) * 7 + c];
            for (int o = 32; o >= 1; o >>= 1) p += __shfl_xor(p, o, 64);
            part[c] = p;
        }
        if (lane == 0)
            for (int c = 0; c < 7; c++) atomicAdd(&sacc[c], a0 * part[c]);
    }
    __syncthreads();
    if (t == 0) {
        float v[7], m = -1e30f, ssum = 0.f;
        for (int c = 0; c < 7; c++) { v[c] = sacc[c]; if (v[c] > m) m = v[c]; }
        for (int c = 0; c < 7; c++) { v[c] = expf(v[c] - m); ssum += v[c]; }
        for (int c = 0; c < 7; c++) out[c] = v[c] / ssum;
    }
}

extern "C" void kernel_launch(void* const* d_in, const int* in_sizes, int n_in,
                              void* d_out, int out_size, void* d_ws, size_t ws_size,
                              hipStream_t stream) {
    const float* x     = (const float*)d_in[0];
    const float* embed = (const float*)d_in[1];
    const float* adjd  = (const float*)d_in[2];
    const float* noise = (const float*)d_in[3];
    const float* tmp   = (const float*)d_in[4];
    const float* W1e   = (const float*)d_in[5];
    const float* b1e   = (const float*)d_in[6];
    const float* W2e   = (const float*)d_in[7];
    const float* b2e   = (const float*)d_in[8];
    const float* Wg0   = (const float*)d_in[9];
    const float* Wg1   = (const float*)d_in[10];
    const void*  rowp  = d_in[11];
    const void*  colp  = d_in[12];
    const int*   nodep = (const int*)d_in[13];
    int E = in_sizes[3];   // noise is float32[E]

    char* w = (char*)d_ws;
    size_t off = 0;
    auto alloc = [&](size_t bytes) -> char* {
        char* p = w + off;
        off = (off + bytes + 255) & ~(size_t)255;
        return p;
    };
    float*        cself   = (float*)alloc(64 * 4);
    float*        cnt0n   = (float*)alloc(SMAX * 4);
    int*          slotmap = (int*)  alloc((size_t)NNODES * 4);
    float*        U       = (float*)alloc((size_t)NNODES * 64 * 4);
    float*        V       = (float*)alloc((size_t)NNODES * 64 * 4);
    float*        xw      = (float*)alloc((size_t)NNODES * DIM * 4);
    unsigned int* list    = (unsigned int*)alloc((size_t)E * 4);
    char*         zstart  = w + off;
    int*          flags   = (int*)  alloc(256);
    float*        cnt0    = (float*)alloc((size_t)NNODES * 4);
    float*        f0s     = (float*)alloc(SMAX * 4);
    float*        r0s     = (float*)alloc(SMAX * 4);
    unsigned int* hashK   = (unsigned int*)alloc((size_t)HSIZE * 4);
    float*        hashC   = (float*)alloc((size_t)HSIZE * 4);
    float*        hashF   = (float*)alloc((size_t)HSIZE * 4);
    float*        hashR   = (float*)alloc((size_t)HSIZE * 4);
    float*        h1acc   = (float*)alloc((size_t)SMAX * DIM * 4);
    size_t zbytes  = (size_t)((w + off) - zstart);
    int n4 = (int)(zbytes / 16);

    k_zero<<<(n4 + 255) / 256, 256, 0, stream>>>((float4*)zstart, n4);
    k_dense<<<2049, 128, 0, stream>>>(embed, x, W1e, b1e, Wg0, nodep,
                                      U, V, xw, cself);
    k_scan_mark<<<512, 256, 0, stream>>>(rowp, colp, adjd, nodep, cnt0, E);
    k_compact<<<NNODES / 256, 256, 0, stream>>>(nodep, cnt0, flags, slotmap, cnt0n);
    k_scan_filter<<<1024, 256, 0, stream>>>(rowp, colp, adjd, nodep, slotmap, flags,
                                            list, hashK, hashC, E);
    k_gates_list<<<512, 256, 0, stream>>>(rowp, colp, list, noise, U, V, cself,
                                          W2e, b2e, tmp, flags, slotmap, hashK,
                                          hashF, hashR, f0s, r0s);
    k_hagg<<<HSIZE / 2, 256, 0, stream>>>(hashK, hashC, hashF, hashR, xw, h1acc);
    k_final<<<1, 256, 0, stream>>>(flags, h1acc, cnt0n, f0s, r0s, Wg1, (float*)d_out);
}